// Round 8
// baseline (520.242 us; speedup 1.0000x reference)
//
#include <hip/hip_runtime.h>
#include <cstdint>

#define IND 128
#define HID 64
#define NEG_SLOPE 0.2f
#define LSTRIDE 132   // 128 + 4: 16B-aligned rows for LDS GEMM tiles
#define EPB 4096      // edges per sort block
#define CBSHIFT 8     // coarse bucket = 256 consecutive dst nodes
#define GNODES 64     // dst nodes per gather block (quarter bucket)

// ---------------------------------------------------------------------------
// K1: h = x @ W.T ; a_src = h @ att_src ; a_dst = h @ att_dst
// Tiled GEMM: block = 64 nodes x 64 hid x K=128, microtile 4x4.
// ---------------------------------------------------------------------------
__global__ __launch_bounds__(256) void k_proj(
    const float* __restrict__ x, const float* __restrict__ W,
    const float* __restrict__ att_s, const float* __restrict__ att_d,
    float* __restrict__ h, float* __restrict__ a_src, float* __restrict__ a_dst,
    int n)
{
  __shared__ float xs[64 * LSTRIDE];
  __shared__ float wt[64 * LSTRIDE];
  __shared__ float sa_l[64], sd_l[64];

  const int tid = threadIdx.x;
  const int nodeBase = blockIdx.x * 64;

  if (tid < 64) { sa_l[tid] = 0.f; sd_l[tid] = 0.f; }

#pragma unroll
  for (int it = 0; it < 8; ++it) {
    int fi = (it * 256 + tid) * 4;
    int hid = fi >> 7, k = fi & 127;
    float4 v = *(const float4*)(W + fi);
    *(float4*)&wt[hid * LSTRIDE + k] = v;
  }
#pragma unroll
  for (int it = 0; it < 8; ++it) {
    int fi = (it * 256 + tid) * 4;
    int nl = fi >> 7, k = fi & 127;
    int node = nodeBase + nl; if (node >= n) node = n - 1;
    float4 v = *(const float4*)(x + (size_t)node * IND + k);
    *(float4*)&xs[nl * LSTRIDE + k] = v;
  }
  __syncthreads();

  const int ng = tid & 15;
  const int hg = tid >> 4;
  const float* xrow0 = &xs[(4 * ng) * LSTRIDE];
  const float* wrow0 = &wt[(4 * hg) * LSTRIDE];

  float acc[4][4];
#pragma unroll
  for (int j = 0; j < 4; ++j)
#pragma unroll
    for (int i = 0; i < 4; ++i) acc[j][i] = 0.f;

  for (int k = 0; k < IND; k += 4) {
    float4 a[4], b[4];
#pragma unroll
    for (int j = 0; j < 4; ++j) a[j] = *(const float4*)(xrow0 + j * LSTRIDE + k);
#pragma unroll
    for (int i = 0; i < 4; ++i) b[i] = *(const float4*)(wrow0 + i * LSTRIDE + k);
#pragma unroll
    for (int j = 0; j < 4; ++j)
#pragma unroll
      for (int i = 0; i < 4; ++i) {
        acc[j][i] = fmaf(a[j].x, b[i].x, acc[j][i]);
        acc[j][i] = fmaf(a[j].y, b[i].y, acc[j][i]);
        acc[j][i] = fmaf(a[j].z, b[i].z, acc[j][i]);
        acc[j][i] = fmaf(a[j].w, b[i].w, acc[j][i]);
      }
  }

#pragma unroll
  for (int j = 0; j < 4; ++j) {
    int node = nodeBase + 4 * ng + j;
    if (node < n)
      *(float4*)(h + (size_t)node * HID + 4 * hg) =
          make_float4(acc[j][0], acc[j][1], acc[j][2], acc[j][3]);
  }

  float4 as4 = *(const float4*)(att_s + 4 * hg);
  float4 ad4 = *(const float4*)(att_d + 4 * hg);
#pragma unroll
  for (int j = 0; j < 4; ++j) {
    float ps = acc[j][0]*as4.x + acc[j][1]*as4.y + acc[j][2]*as4.z + acc[j][3]*as4.w;
    float pd = acc[j][0]*ad4.x + acc[j][1]*ad4.y + acc[j][2]*ad4.z + acc[j][3]*ad4.w;
    ps += __shfl_xor(ps, 16, 64); ps += __shfl_xor(ps, 32, 64);
    pd += __shfl_xor(pd, 16, 64); pd += __shfl_xor(pd, 32, 64);
    if ((tid & 63) < 16) {
      atomicAdd(&sa_l[4 * ng + j], ps);
      atomicAdd(&sd_l[4 * ng + j], pd);
    }
  }
  __syncthreads();
  if (tid < 64) {
    int node = nodeBase + tid;
    if (node < n) { a_src[node] = sa_l[tid]; a_dst[node] = sd_l[tid]; }
  }
}

// ---------------------------------------------------------------------------
// K2: per-(sort block, coarse bucket) histogram. cnt bucket-major.
// ---------------------------------------------------------------------------
__global__ __launch_bounds__(256) void k_cnt(
    const int* __restrict__ ei, int* __restrict__ cnt,
    int E, long long E2, int nblk, int nbuck)
{
  __shared__ int hist[256];
  const int tid = threadIdx.x;
  hist[tid] = 0;
  __syncthreads();

  const long long i0 = (long long)blockIdx.x * EPB;
  const int cntE = (int)((E2 - i0 < EPB) ? (E2 - i0) : EPB);
  for (int j = tid; j < cntE; j += 256) {
    long long idx = i0 + j;
    int d = (idx < E) ? ei[E + idx] : (int)(idx - E);
    atomicAdd(&hist[d >> CBSHIFT], 1);
  }
  __syncthreads();
  if (tid < nbuck) cnt[tid * nblk + blockIdx.x] = hist[tid];
}

// ---------------------------------------------------------------------------
// K3a/b/c: multi-block exclusive scan of cnt[0..cntN) -> cntS.
// ---------------------------------------------------------------------------
__global__ __launch_bounds__(256) void k_scan_a(
    const int* __restrict__ vals, int* __restrict__ blockSums, int cntN)
{
  __shared__ int red[4];
  int i = blockIdx.x * 256 + threadIdx.x;
  int v = (i < cntN) ? vals[i] : 0;
#pragma unroll
  for (int o = 32; o; o >>= 1) v += __shfl_xor(v, o, 64);
  if ((threadIdx.x & 63) == 0) red[threadIdx.x >> 6] = v;
  __syncthreads();
  if (threadIdx.x == 0)
    blockSums[blockIdx.x] = red[0] + red[1] + red[2] + red[3];
}

__global__ __launch_bounds__(1024) void k_scan_b(
    int* __restrict__ blockSums, int nb)
{
  __shared__ int sums[1024];
  const int tid = threadIdx.x;
  int v = (tid < nb) ? blockSums[tid] : 0;
  sums[tid] = v;
  __syncthreads();
  for (int off = 1; off < 1024; off <<= 1) {
    int t = (tid >= off) ? sums[tid - off] : 0;
    __syncthreads();
    sums[tid] += t;
    __syncthreads();
  }
  if (tid < nb) blockSums[tid] = sums[tid] - v;
}

__global__ __launch_bounds__(256) void k_scan_c(
    const int* __restrict__ vals, const int* __restrict__ blockSums,
    int* __restrict__ out, int cntN)
{
  __shared__ int sums[256];
  const int tid = threadIdx.x;
  int i = blockIdx.x * 256 + tid;
  int v = (i < cntN) ? vals[i] : 0;
  sums[tid] = v;
  __syncthreads();
  for (int off = 1; off < 256; off <<= 1) {
    int t = (tid >= off) ? sums[tid - off] : 0;
    __syncthreads();
    sums[tid] += t;
    __syncthreads();
  }
  if (i < cntN) out[i] = sums[tid] - v + blockSums[blockIdx.x];
}

// ---------------------------------------------------------------------------
// K4: block-level counting sort of EPB edges by coarse bucket, then LINEAR
// write-out (block owns each run -> lines fill). Packed 4B: (dst<<16)|src.
// ---------------------------------------------------------------------------
__global__ __launch_bounds__(256) void k_sortout(
    const int* __restrict__ ei, const int* __restrict__ cntS,
    unsigned* __restrict__ tmp, int E, long long E2, int nblk, int nbuck)
{
  __shared__ int hist[256];
  __shared__ int sums[256];
  __shared__ int cur[256];
  __shared__ int gbase[256];
  __shared__ unsigned sorted[EPB];

  const int tid = threadIdx.x;
  hist[tid] = 0;
  __syncthreads();

  const long long i0 = (long long)blockIdx.x * EPB;

  unsigned pk[EPB / 256];
#pragma unroll
  for (int j = 0; j < EPB / 256; ++j) {
    long long idx = i0 + j * 256 + tid;
    unsigned v = 0xFFFFFFFFu;
    if (idx < E2) {
      int s, d;
      if (idx < E) { s = ei[idx]; d = ei[E + idx]; }
      else         { s = d = (int)(idx - E); }
      v = ((unsigned)d << 16) | (unsigned)s;
      atomicAdd(&hist[d >> CBSHIFT], 1);
    }
    pk[j] = v;
  }
  __syncthreads();

  sums[tid] = hist[tid];
  __syncthreads();
  for (int off = 1; off < 256; off <<= 1) {
    int t = (tid >= off) ? sums[tid - off] : 0;
    __syncthreads();
    sums[tid] += t;
    __syncthreads();
  }
  const int lstart_t = sums[tid] - hist[tid];
  cur[tid] = lstart_t;
  gbase[tid] = (tid < nbuck) ? cntS[tid * nblk + blockIdx.x] : 0;
  __syncthreads();
  hist[tid] = lstart_t;
  __syncthreads();

#pragma unroll
  for (int j = 0; j < EPB / 256; ++j) {
    unsigned v = pk[j];
    if (v != 0xFFFFFFFFu) {
      int b = v >> (16 + CBSHIFT);
      int lpos = atomicAdd(&cur[b], 1);
      sorted[lpos] = v;
    }
  }
  __syncthreads();

  const int cntE = (int)((E2 - i0 < EPB) ? (E2 - i0) : EPB);
  for (int i = tid; i < cntE; i += 256) {
    unsigned v = sorted[i];
    int b = v >> (16 + CBSHIFT);
    tmp[gbase[b] + (i - hist[b])] = v;
  }
}

// ---------------------------------------------------------------------------
// K5: fused softmax + aggregate + epilogue. Block owns GNODES=64 dst nodes
// (quarter of a coarse bucket) and accumulates UNnormalized w*h into LDS
// out[dl][lane] via LDS atomics (edge order irrelevant -> no exact CSR
// needed). Scans the parent bucket's tmp run, ballot-compacts its edges
// into an LDS queue per wave, 4x-unrolled broadcast loop for h-load ILP.
// Then normalize /ssum, +bias, relu, dot W_lin, sigmoid, write y.
// ---------------------------------------------------------------------------
__global__ __launch_bounds__(256) void k_gather2(
    const unsigned* __restrict__ tmp, const int* __restrict__ cntS,
    const float* __restrict__ a_src, const float* __restrict__ a_dst,
    const float* __restrict__ h, const float* __restrict__ bias,
    const float* __restrict__ W_lin, const float* __restrict__ b_lin,
    float* __restrict__ y, int E2total, int n, int nblk, int nbuck)
{
  __shared__ float out_l[GNODES * 64];   // [dl][lane]
  __shared__ float ssum_l[GNODES];
  __shared__ float adl[GNODES];
  __shared__ unsigned q_v[4][64];
  __shared__ float    q_w[4][64];

  const int tid  = threadIdx.x;
  const int lane = tid & 63;
  const int wid  = tid >> 6;

  const int pb = blockIdx.x >> 2;                 // parent coarse bucket
  const int n0 = (pb << CBSHIFT) + (blockIdx.x & 3) * GNODES;

#pragma unroll
  for (int i = tid; i < GNODES * 64; i += 256) out_l[i] = 0.f;
  if (tid < GNODES) {
    ssum_l[tid] = 0.f;
    int node = n0 + tid;
    adl[tid] = (node < n) ? a_dst[node] : 0.f;
  }
  __syncthreads();

  const int base = cntS[pb * nblk];
  const int next = (pb + 1 < nbuck) ? cntS[(pb + 1) * nblk] : E2total;

  for (int i0 = base + wid * 64; i0 < next; i0 += 256) {
    int i = i0 + lane;
    int s = 0, dl = -1;
    float wl = 0.f;
    bool valid = false;
    if (i < next) {
      unsigned v = tmp[i];
      dl = (int)(v >> 16) - n0;
      s  = (int)(v & 0xFFFFu);
      valid = ((unsigned)dl < (unsigned)GNODES);
    }
    if (valid) {
      float sc = a_src[s] + adl[dl];
      sc = (sc >= 0.f) ? sc : NEG_SLOPE * sc;
      wl = expf(sc);
      atomicAdd(&ssum_l[dl], wl);
    }
    unsigned long long mask = __ballot(valid);
    int qn = __popcll(mask);
    if (qn == 0) continue;
    if (valid) {
      int pos = __popcll(mask & ((1ull << lane) - 1ull));
      q_v[wid][pos] = ((unsigned)dl << 16) | (unsigned)s;
      q_w[wid][pos] = wl;
    }
    __builtin_amdgcn_wave_barrier();   // same-wave LDS RAW ordering

    int j = 0;
    for (; j + 4 <= qn; j += 4) {
      unsigned v0 = q_v[wid][j], v1 = q_v[wid][j+1];
      unsigned v2 = q_v[wid][j+2], v3 = q_v[wid][j+3];
      float w0 = q_w[wid][j], w1 = q_w[wid][j+1];
      float w2 = q_w[wid][j+2], w3 = q_w[wid][j+3];
      float h0 = h[(size_t)(v0 & 0xFFFFu) * HID + lane];
      float h1 = h[(size_t)(v1 & 0xFFFFu) * HID + lane];
      float h2 = h[(size_t)(v2 & 0xFFFFu) * HID + lane];
      float h3 = h[(size_t)(v3 & 0xFFFFu) * HID + lane];
      atomicAdd(&out_l[(v0 >> 16) * 64 + lane], w0 * h0);
      atomicAdd(&out_l[(v1 >> 16) * 64 + lane], w1 * h1);
      atomicAdd(&out_l[(v2 >> 16) * 64 + lane], w2 * h2);
      atomicAdd(&out_l[(v3 >> 16) * 64 + lane], w3 * h3);
    }
    for (; j < qn; ++j) {
      unsigned v0 = q_v[wid][j];
      float w0 = q_w[wid][j];
      float h0 = h[(size_t)(v0 & 0xFFFFu) * HID + lane];
      atomicAdd(&out_l[(v0 >> 16) * 64 + lane], w0 * h0);
    }
    __builtin_amdgcn_wave_barrier();
  }
  __syncthreads();

  // epilogue: each wave handles 16 nodes
  const float bl = bias[lane];
  const float wlin = W_lin[lane];
  const float b0 = b_lin[0];
  for (int t = 0; t < 16; ++t) {
    int nl = wid * 16 + t;
    int node = n0 + nl;
    if (node >= n) break;
    float inv = 1.f / ssum_l[nl];
    float v = fmaxf(out_l[nl * 64 + lane] * inv + bl, 0.f);
    float z = v * wlin;
#pragma unroll
    for (int o = 32; o; o >>= 1) z += __shfl_xor(z, o, 64);
    if (lane == 0)
      y[node] = 1.f / (1.f + expf(-(z + b0)));
  }
}

// ---------------------------------------------------------------------------

extern "C" void kernel_launch(void* const* d_in, const int* in_sizes, int n_in,
                              void* d_out, int out_size, void* d_ws, size_t ws_size,
                              hipStream_t stream)
{
  const float* x     = (const float*)d_in[0];
  const int*   ei    = (const int*)d_in[1];
  const float* W     = (const float*)d_in[2];
  const float* att_s = (const float*)d_in[3];
  const float* att_d = (const float*)d_in[4];
  const float* bias  = (const float*)d_in[5];
  const float* W_lin = (const float*)d_in[6];
  const float* b_lin = (const float*)d_in[7];
  float* y = (float*)d_out;

  const int n = in_sizes[0] / IND;
  const int E = in_sizes[1] / 2;
  const long long E2 = (long long)E + n;
  const int nblk  = (int)((E2 + EPB - 1) / EPB);         // sort blocks (208)
  const int nbuck = (n + (1 << CBSHIFT) - 1) >> CBSHIFT; // coarse buckets (196)
  const int cntN  = nbuck * nblk;                        // cnt matrix (40768)
  const int nbs   = (cntN + 255) / 256;                  // scan blocks (160)

  // Workspace (~17 MB). Every buffer fully written before read, every call.
  char* ws = (char*)d_ws;
  float*    h      = (float*)ws;    ws += (size_t)n * HID * sizeof(float);
  float*    a_src  = (float*)ws;    ws += (size_t)n * sizeof(float);
  float*    a_dst  = (float*)ws;    ws += (size_t)n * sizeof(float);
  int*      cnt    = (int*)ws;      ws += (size_t)cntN * sizeof(int);
  int*      cntS   = (int*)ws;      ws += (size_t)cntN * sizeof(int);
  int*      bsums  = (int*)ws;      ws += (size_t)1024 * sizeof(int);
  unsigned* tmp    = (unsigned*)ws; ws += (size_t)E2 * sizeof(unsigned);

  k_cnt<<<nblk, 256, 0, stream>>>(ei, cnt, E, E2, nblk, nbuck);
  k_scan_a<<<nbs, 256, 0, stream>>>(cnt, bsums, cntN);
  k_scan_b<<<1, 1024, 0, stream>>>(bsums, nbs);
  k_scan_c<<<nbs, 256, 0, stream>>>(cnt, bsums, cntS, cntN);

  k_proj<<<(n + 63) / 64, 256, 0, stream>>>(x, W, att_s, att_d, h, a_src, a_dst, n);

  k_sortout<<<nblk, 256, 0, stream>>>(ei, cntS, tmp, E, E2, nblk, nbuck);

  k_gather2<<<nbuck * 4, 256, 0, stream>>>(
      tmp, cntS, a_src, a_dst, h, bias, W_lin, b_lin, y, (int)E2, n, nblk, nbuck);
}